// Round 3
// baseline (4364.732 us; speedup 1.0000x reference)
//
#include <hip/hip_runtime.h>

using u16 = unsigned short;
using u32 = unsigned int;

typedef _Float16 f16x2 __attribute__((ext_vector_type(2)));
typedef _Float16 f16x8 __attribute__((ext_vector_type(8)));
typedef float    f32x4 __attribute__((ext_vector_type(4)));

__device__ __forceinline__ u16 f16bits(float x) {
  union { _Float16 h; u16 u; } r; r.h = (_Float16)x; return r.u;
}
__device__ __forceinline__ float h2f(u16 v) {
  union { u16 u; _Float16 h; } r; r.u = v; return (float)r.h;
}
__device__ __forceinline__ u32 pack2(float a, float b) {
  union { f16x2 h; u32 u; } r; r.h.x = (_Float16)a; r.h.y = (_Float16)b; return r.u;
}
__device__ __forceinline__ float fdot2a(u32 a, u32 b, float c) {
  union { u32 u; f16x2 h; } ua, ub; ua.u = a; ub.u = b;
#if __has_builtin(__builtin_amdgcn_fdot2)
  return __builtin_amdgcn_fdot2(ua.h, ub.h, c, false);
#else
  return c + (float)ua.h.x * (float)ub.h.x + (float)ua.h.y * (float)ub.h.y;
#endif
}
__device__ __forceinline__ float sigmoidf_(float x) { return 1.0f / (1.0f + __expf(-x)); }
__device__ __forceinline__ float tanhf_(float x)    { return 1.0f - 2.0f / (__expf(2.0f * x) + 1.0f); }

__device__ __forceinline__ f16x8 lds16(const u16* p) {
  union { uint4 u; f16x8 h; } r; r.u = *(const uint4*)p; return r.h;
}

// ---------------- prep: build f16 weight layouts + zero state ----------------
// WxT[n][k]   : [1024][256] f16, transposed input-proj weights
// Whpp[i4][t] : [32][1024] uint4 — per-(rec-)thread gathered W_h pair groups.
//   thread t: w=t>>6, l=t&63, q=l>>4, hcol=w*16+(l&15); i4=g*8+pp (g=gate);
//   element e of uint4 = f16x2 pair kk=q*32+pp*4+e of column hcol of gate-g W_h.
// h16s        : [128][128] u32 pairs of h state, zeroed
// c_s         : [128][256] f32, zeroed
__global__ void lstm_prep(const float* __restrict__ Wxi, const float* __restrict__ Wxf,
                          const float* __restrict__ Wxg, const float* __restrict__ Wxo,
                          const float* __restrict__ Whi, const float* __restrict__ Whf,
                          const float* __restrict__ Whg, const float* __restrict__ Who,
                          u16* __restrict__ WxT, u32* __restrict__ Whpp,
                          u32* __restrict__ h16s, float* __restrict__ c_s) {
  int idx = blockIdx.x * 256 + threadIdx.x;
  if (idx < 262144) {                       // WxT
    int n = idx >> 8, k = idx & 255;
    int g = n >> 8;
    const float* W = (g == 0) ? Wxi : (g == 1) ? Wxf : (g == 2) ? Wxg : Wxo;
    WxT[idx] = f16bits(W[k * 256 + (n & 255)]);
  } else if (idx < 262144 + 131072) {       // Whpp (u32-granular writes)
    int i2 = idx - 262144;
    int e = i2 & 3, tmp = i2 >> 2;
    int t = tmp & 1023, i4 = tmp >> 10;
    int g = i4 >> 3, pp = i4 & 7;
    int w = t >> 6, l = t & 63, q = l >> 4;
    int col = w * 16 + (l & 15);            // hidden unit owned by thread t
    int kk = q * 32 + pp * 4 + e;
    const float* W = (g == 0) ? Whi : (g == 1) ? Whf : (g == 2) ? Whg : Who;
    u32 lo = f16bits(W[(2 * kk) * 256 + col]);
    u32 hi = f16bits(W[(2 * kk + 1) * 256 + col]);
    Whpp[i2] = lo | (hi << 16);
  } else if (idx < 262144 + 131072 + 16384) {
    h16s[idx - 393216] = 0u;
  } else if (idx < 262144 + 131072 + 16384 + 32768) {
    c_s[idx - 409600] = 0.0f;
  }
}

// ---------------- input-projection GEMM (unchanged) --------------------------
__global__ __launch_bounds__(256) void proj_gemm(
    const float* __restrict__ x, const u16* __restrict__ WxT,
    u16* __restrict__ gates, const float* __restrict__ bi,
    const float* __restrict__ bf, const float* __restrict__ bg,
    const float* __restrict__ bo, int t0, int tcShift) {
  __shared__ u16 Al[128 * 72];
  __shared__ u16 Bl[128 * 72];
  const int tid = threadIdx.x;
  const int lane = tid & 63, wv = tid >> 6;
  const int wr = wv >> 1, wc = wv & 1;
  const int m0 = blockIdx.x * 128, n0 = blockIdx.y * 128;
  const int tcMask = (1 << tcShift) - 1;
  f32x4 acc[4][4] = {};
  for (int k0 = 0; k0 < 256; k0 += 64) {
#pragma unroll
    for (int p = 0; p < 8; ++p) {
      int flat = p * 256 + tid;
      int r = flat >> 4, cc = flat & 15;
      int m = m0 + r;
      int b = m >> tcShift, tc = m & tcMask;
      const float4 xv = *(const float4*)(x + (size_t)(b * 1024 + t0 + tc) * 256 + k0 + cc * 4);
      uint2 w2 = make_uint2(pack2(xv.x, xv.y), pack2(xv.z, xv.w));
      *(uint2*)&Al[r * 72 + cc * 4] = w2;
    }
#pragma unroll
    for (int p = 0; p < 8; ++p) {
      int flat = p * 256 + tid;
      int r = flat >> 4, cc = flat & 15;
      uint2 w2 = *(const uint2*)(WxT + (size_t)(n0 + r) * 256 + k0 + cc * 4);
      *(uint2*)&Bl[r * 72 + cc * 4] = w2;
    }
    __syncthreads();
#pragma unroll
    for (int kk = 0; kk < 64; kk += 32) {
      f16x8 af[4], bfr[4];
#pragma unroll
      for (int i = 0; i < 4; ++i) {
        af[i]  = lds16(&Al[(wr * 64 + i * 16 + (lane & 15)) * 72 + kk + (lane >> 4) * 8]);
        bfr[i] = lds16(&Bl[(wc * 64 + i * 16 + (lane & 15)) * 72 + kk + (lane >> 4) * 8]);
      }
#pragma unroll
      for (int mi = 0; mi < 4; ++mi)
#pragma unroll
        for (int ni = 0; ni < 4; ++ni)
          acc[mi][ni] = __builtin_amdgcn_mfma_f32_16x16x32_f16(af[mi], bfr[ni], acc[mi][ni], 0, 0, 0);
    }
    __syncthreads();
  }
#pragma unroll
  for (int ni = 0; ni < 4; ++ni) {
    int n = n0 + wc * 64 + ni * 16 + (lane & 15);
    int g = n >> 8;
    const float* bp = (g == 0) ? bi : (g == 1) ? bf : (g == 2) ? bg : bo;
    float bias = bp[n & 255];
#pragma unroll
    for (int mi = 0; mi < 4; ++mi) {
#pragma unroll
      for (int ri = 0; ri < 4; ++ri) {
        int m = m0 + wr * 64 + mi * 16 + (lane >> 4) * 4 + ri;
        gates[(size_t)m * 1024 + n] = f16bits(acc[mi][ni][ri] + bias);
      }
    }
  }
}

// ---------------- persistent per-batch recurrence ----------------------------
// 1024 threads. thread t (w=t>>6, l=t&63, q=l>>4): owns hidden unit
// hcol=w*16+(l&15), computes K-quarter-q partial dots for its 4 gate columns
// (hcol+256g). After shfl_xor(16,32) every lane has the full z for all 4 gates
// -> inline c/h update (replicated across the 4 quarter lanes), q==0 writes h.
// Weight pairs: pp 0..6 in regs (112 u32), pp==7 in LDS (1 uint4/gate/thread).
// ONE barrier per step.
__global__ __launch_bounds__(1024) void lstm_rec(
    const u32* __restrict__ Whpp, const u16* __restrict__ gates,
    u32* __restrict__ h16s, float* __restrict__ c_s,
    const float* __restrict__ Why, const float* __restrict__ by,
    float* __restrict__ out, int Tc, int last) {
  extern __shared__ unsigned char smem[];
  uint4* ldsW = (uint4*)smem;                       // [4][1024] uint4 = 65536 B
  u32*   hq   = (u32*)(smem + 65536);               // [2][4*40] u32   = 1280 B
  const int b = blockIdx.x, t = threadIdx.x;
  const int l = t & 63, w = t >> 6, q = l >> 4;
  const int hcol = w * 16 + (l & 15);

  // gather weights: 32 coalesced uint4 loads; pp<7 -> regs, pp==7 -> LDS
  u32 wreg[112];
  const uint4* Wp4 = (const uint4*)Whpp;
#pragma unroll
  for (int i4 = 0; i4 < 32; ++i4) {
    uint4 v = Wp4[i4 * 1024 + t];
    const int g = i4 >> 3, pp = i4 & 7;
    if (pp < 7) {
      wreg[g * 28 + pp * 4 + 0] = v.x;
      wreg[g * 28 + pp * 4 + 1] = v.y;
      wreg[g * 28 + pp * 4 + 2] = v.z;
      wreg[g * 28 + pp * 4 + 3] = v.w;
    } else {
      ldsW[g * 1024 + t] = v;
    }
  }
  if (t < 128) hq[(t >> 5) * 40 + (t & 31)] = h16s[b * 128 + t];
  float c = c_s[b * 256 + hcol];                    // replicated across quarters
  const u16* gxp = gates + (size_t)b * Tc * 1024 + hcol;
  u16 pre0 = gxp[0], pre1 = gxp[256], pre2 = gxp[512], pre3 = gxp[768];
  int buf = 0;
  __syncthreads();

  for (int tc = 0; tc < Tc; ++tc) {
    const u16 cur0 = pre0, cur1 = pre1, cur2 = pre2, cur3 = pre3;
    if (tc + 1 < Tc) {
      const u16* gn = gxp + (size_t)(tc + 1) * 1024;
      pre0 = gn[0]; pre1 = gn[256]; pre2 = gn[512]; pre3 = gn[768];
    }
    float acc0 = 0.f, acc1 = 0.f, acc2 = 0.f, acc3 = 0.f;
    const uint4* hb = (const uint4*)(hq + buf * 160 + q * 40);
#pragma unroll
    for (int u = 0; u < 8; ++u) {
      uint4 hv = hb[u];
      uint4 w0, w1, w2, w3;
      if (u < 7) {
        w0 = make_uint4(wreg[0 * 28 + u * 4], wreg[0 * 28 + u * 4 + 1], wreg[0 * 28 + u * 4 + 2], wreg[0 * 28 + u * 4 + 3]);
        w1 = make_uint4(wreg[1 * 28 + u * 4], wreg[1 * 28 + u * 4 + 1], wreg[1 * 28 + u * 4 + 2], wreg[1 * 28 + u * 4 + 3]);
        w2 = make_uint4(wreg[2 * 28 + u * 4], wreg[2 * 28 + u * 4 + 1], wreg[2 * 28 + u * 4 + 2], wreg[2 * 28 + u * 4 + 3]);
        w3 = make_uint4(wreg[3 * 28 + u * 4], wreg[3 * 28 + u * 4 + 1], wreg[3 * 28 + u * 4 + 2], wreg[3 * 28 + u * 4 + 3]);
      } else {
        w0 = ldsW[0 * 1024 + t];
        w1 = ldsW[1 * 1024 + t];
        w2 = ldsW[2 * 1024 + t];
        w3 = ldsW[3 * 1024 + t];
      }
      acc0 = fdot2a(hv.x, w0.x, acc0); acc0 = fdot2a(hv.y, w0.y, acc0);
      acc0 = fdot2a(hv.z, w0.z, acc0); acc0 = fdot2a(hv.w, w0.w, acc0);
      acc1 = fdot2a(hv.x, w1.x, acc1); acc1 = fdot2a(hv.y, w1.y, acc1);
      acc1 = fdot2a(hv.z, w1.z, acc1); acc1 = fdot2a(hv.w, w1.w, acc1);
      acc2 = fdot2a(hv.x, w2.x, acc2); acc2 = fdot2a(hv.y, w2.y, acc2);
      acc2 = fdot2a(hv.z, w2.z, acc2); acc2 = fdot2a(hv.w, w2.w, acc2);
      acc3 = fdot2a(hv.x, w3.x, acc3); acc3 = fdot2a(hv.y, w3.y, acc3);
      acc3 = fdot2a(hv.z, w3.z, acc3); acc3 = fdot2a(hv.w, w3.w, acc3);
    }
    // full cross-quarter reduction: afterwards ALL lanes hold complete sums
    acc0 += __shfl_xor(acc0, 16); acc0 += __shfl_xor(acc0, 32);
    acc1 += __shfl_xor(acc1, 16); acc1 += __shfl_xor(acc1, 32);
    acc2 += __shfl_xor(acc2, 16); acc2 += __shfl_xor(acc2, 32);
    acc3 += __shfl_xor(acc3, 16); acc3 += __shfl_xor(acc3, 32);
    // inline gate math (identical in all 4 quarter lanes of this unit)
    float zi = acc0 + h2f(cur0);
    float zf = acc1 + h2f(cur1);
    float zg = acc2 + h2f(cur2);
    float zo = acc3 + h2f(cur3);
    float i_ = sigmoidf_(zi), f_ = sigmoidf_(zf), g_ = tanhf_(zg), o_ = sigmoidf_(zo);
    c = f_ * c + i_ * g_;
    float h_ = o_ * tanhf_(c);
    if (l < 16) {                                   // q==0 publishes h
      const int kk = hcol >> 1;
      ((u16*)hq)[((buf ^ 1) * 160 + (kk >> 5) * 40 + (kk & 31)) * 2 + (hcol & 1)] = f16bits(h_);
    }
    buf ^= 1;
    __syncthreads();
  }

  if (t < 128) h16s[b * 128 + t] = hq[buf * 160 + (t >> 5) * 40 + (t & 31)];
  if (l < 16) c_s[b * 256 + hcol] = c;

  if (last && t < 128) {                    // y = h_T @ W_hy + b_y
    float acc = by[t];
    const u16* hh = (const u16*)(hq + buf * 160);
#pragma unroll 8
    for (int k = 0; k < 256; ++k) {
      float hv = h2f(hh[((k >> 6) * 40 + ((k >> 1) & 31)) * 2 + (k & 1)]);
      acc += hv * Why[k * 128 + t];
    }
    out[b * 128 + t] = acc;
  }
}

extern "C" void kernel_launch(void* const* d_in, const int* in_sizes, int n_in,
                              void* d_out, int out_size, void* d_ws, size_t ws_size,
                              hipStream_t stream) {
  const float* x   = (const float*)d_in[0];
  const float* Wxi = (const float*)d_in[1];
  const float* Whi = (const float*)d_in[2];
  const float* b_i = (const float*)d_in[3];
  const float* Wxf = (const float*)d_in[4];
  const float* Whf = (const float*)d_in[5];
  const float* b_f = (const float*)d_in[6];
  const float* Wxg = (const float*)d_in[7];
  const float* Whg = (const float*)d_in[8];
  const float* b_g = (const float*)d_in[9];
  const float* Wxo = (const float*)d_in[10];
  const float* Who = (const float*)d_in[11];
  const float* b_o = (const float*)d_in[12];
  const float* Why = (const float*)d_in[13];
  const float* b_y = (const float*)d_in[14];
  float* out = (float*)d_out;

  int Tc = 256;
  while (Tc > 32 && (size_t)128 * Tc * 1024 * 2 + 1245184ull > ws_size) Tc >>= 1;
  const int tcShift = __builtin_ctz((unsigned)Tc);
  const int nch = 1024 / Tc;

  char* wsb = (char*)d_ws;
  const size_t gbytes = (size_t)128 * Tc * 1024 * 2;
  u16*   gates16 = (u16*)wsb;
  u16*   WxT     = (u16*)(wsb + gbytes);
  u32*   Whpp    = (u32*)(wsb + gbytes + 524288);
  u32*   h16s    = (u32*)(wsb + gbytes + 1048576);
  float* c_s     = (float*)(wsb + gbytes + 1048576 + 65536);

  const int recLds = 65536 + 1280;
  (void)hipFuncSetAttribute((const void*)lstm_rec,
                            hipFuncAttributeMaxDynamicSharedMemorySize, recLds);

  lstm_prep<<<1728, 256, 0, stream>>>(Wxi, Wxf, Wxg, Wxo, Whi, Whf, Whg, Who,
                                      WxT, Whpp, h16s, c_s);
  for (int ci = 0; ci < nch; ++ci) {
    int t0 = ci * Tc;
    proj_gemm<<<dim3(Tc, 8), 256, 0, stream>>>(x, WxT, gates16, b_i, b_f, b_g, b_o,
                                               t0, tcShift);
    lstm_rec<<<128, 1024, recLds, stream>>>(Whpp, gates16, h16s, c_s, Why, b_y, out,
                                            Tc, (ci == nch - 1) ? 1 : 0);
  }
}

// Round 4
// 2617.364 us; speedup vs baseline: 1.6676x; 1.6676x over previous
//
#include <hip/hip_runtime.h>

using u16 = unsigned short;
using u32 = unsigned int;

typedef _Float16 f16x2 __attribute__((ext_vector_type(2)));
typedef _Float16 f16x8 __attribute__((ext_vector_type(8)));
typedef float    f32x4 __attribute__((ext_vector_type(4)));

__device__ __forceinline__ u16 f16bits(float x) {
  union { _Float16 h; u16 u; } r; r.h = (_Float16)x; return r.u;
}
__device__ __forceinline__ float h2f(u16 v) {
  union { u16 u; _Float16 h; } r; r.u = v; return (float)r.h;
}
__device__ __forceinline__ u32 pack2(float a, float b) {
  union { f16x2 h; u32 u; } r; r.h.x = (_Float16)a; r.h.y = (_Float16)b; return r.u;
}
__device__ __forceinline__ float fdot2a(u32 a, u32 b, float c) {
  union { u32 u; f16x2 h; } ua, ub; ua.u = a; ub.u = b;
#if __has_builtin(__builtin_amdgcn_fdot2)
  return __builtin_amdgcn_fdot2(ua.h, ub.h, c, false);
#else
  return c + (float)ua.h.x * (float)ub.h.x + (float)ua.h.y * (float)ub.h.y;
#endif
}
__device__ __forceinline__ float sigmoidf_(float x) { return 1.0f / (1.0f + __expf(-x)); }
__device__ __forceinline__ float tanhf_(float x)    { return 1.0f - 2.0f / (__expf(2.0f * x) + 1.0f); }

__device__ __forceinline__ f16x8 lds16(const u16* p) {
  union { uint4 u; f16x8 h; } r; r.u = *(const uint4*)p; return r.h;
}

// Cross-quarter reduce on the VALU pipe (permlane swaps), not LDS (bpermute).
// After this, ALL 64 lanes hold sum over the 4 sixteen-lane quarter groups.
__device__ __forceinline__ float qreduce(float a) {
#if __has_builtin(__builtin_amdgcn_permlane16_swap) && __has_builtin(__builtin_amdgcn_permlane32_swap)
  typedef unsigned uv2 __attribute__((ext_vector_type(2)));
  union { float f; unsigned u; } x, p, q;
  x.f = a;
  uv2 r1 = __builtin_amdgcn_permlane16_swap(x.u, x.u, false, false);
  p.u = r1[0]; q.u = r1[1];
  float s = p.f + q.f;                 // == a + xor16(a) in every lane
  x.f = s;
  uv2 r2 = __builtin_amdgcn_permlane32_swap(x.u, x.u, false, false);
  p.u = r2[0]; q.u = r2[1];
  return p.f + q.f;                    // full sum in every lane
#else
  a += __shfl_xor(a, 16);
  a += __shfl_xor(a, 32);
  return a;
#endif
}

// ---------------- prep: build f16 weight layouts + zero state ----------------
// WxT[n][k]   : [1024][256] f16, transposed input-proj weights
// Whpp[i4][t] : [32][1024] uint4 — per-(rec-)thread gathered W_h pair groups.
//   thread t: w=t>>6, l=t&63, q=l>>4, hcol=w*16+(l&15); i4=g*8+pp (g=gate);
//   element e of uint4 = f16x2 pair kk=q*32+pp*4+e of column hcol of gate-g W_h.
// h16s        : [128][128] u32 pairs of h state, zeroed
// c_s         : [128][256] f32, zeroed
__global__ void lstm_prep(const float* __restrict__ Wxi, const float* __restrict__ Wxf,
                          const float* __restrict__ Wxg, const float* __restrict__ Wxo,
                          const float* __restrict__ Whi, const float* __restrict__ Whf,
                          const float* __restrict__ Whg, const float* __restrict__ Who,
                          u16* __restrict__ WxT, u32* __restrict__ Whpp,
                          u32* __restrict__ h16s, float* __restrict__ c_s) {
  int idx = blockIdx.x * 256 + threadIdx.x;
  if (idx < 262144) {                       // WxT
    int n = idx >> 8, k = idx & 255;
    int g = n >> 8;
    const float* W = (g == 0) ? Wxi : (g == 1) ? Wxf : (g == 2) ? Wxg : Wxo;
    WxT[idx] = f16bits(W[k * 256 + (n & 255)]);
  } else if (idx < 262144 + 131072) {       // Whpp (u32-granular writes)
    int i2 = idx - 262144;
    int e = i2 & 3, tmp = i2 >> 2;
    int t = tmp & 1023, i4 = tmp >> 10;
    int g = i4 >> 3, pp = i4 & 7;
    int w = t >> 6, l = t & 63, q = l >> 4;
    int col = w * 16 + (l & 15);            // hidden unit owned by thread t
    int kk = q * 32 + pp * 4 + e;
    const float* W = (g == 0) ? Whi : (g == 1) ? Whf : (g == 2) ? Whg : Who;
    u32 lo = f16bits(W[(2 * kk) * 256 + col]);
    u32 hi = f16bits(W[(2 * kk + 1) * 256 + col]);
    Whpp[i2] = lo | (hi << 16);
  } else if (idx < 262144 + 131072 + 16384) {
    h16s[idx - 393216] = 0u;
  } else if (idx < 262144 + 131072 + 16384 + 32768) {
    c_s[idx - 409600] = 0.0f;
  }
}

// ---------------- input-projection GEMM --------------------------------------
// NOTE epilogue writes PERMUTED gate layout: gates[m][ (n&255)*4 + (n>>8) ]
// so the recurrence can load its 4 gate pre-acts as one uint2.
__global__ __launch_bounds__(256) void proj_gemm(
    const float* __restrict__ x, const u16* __restrict__ WxT,
    u16* __restrict__ gates, const float* __restrict__ bi,
    const float* __restrict__ bf, const float* __restrict__ bg,
    const float* __restrict__ bo, int t0, int tcShift) {
  __shared__ u16 Al[128 * 72];
  __shared__ u16 Bl[128 * 72];
  const int tid = threadIdx.x;
  const int lane = tid & 63, wv = tid >> 6;
  const int wr = wv >> 1, wc = wv & 1;
  const int m0 = blockIdx.x * 128, n0 = blockIdx.y * 128;
  const int tcMask = (1 << tcShift) - 1;
  f32x4 acc[4][4] = {};
  for (int k0 = 0; k0 < 256; k0 += 64) {
#pragma unroll
    for (int p = 0; p < 8; ++p) {
      int flat = p * 256 + tid;
      int r = flat >> 4, cc = flat & 15;
      int m = m0 + r;
      int b = m >> tcShift, tc = m & tcMask;
      const float4 xv = *(const float4*)(x + (size_t)(b * 1024 + t0 + tc) * 256 + k0 + cc * 4);
      uint2 w2 = make_uint2(pack2(xv.x, xv.y), pack2(xv.z, xv.w));
      *(uint2*)&Al[r * 72 + cc * 4] = w2;
    }
#pragma unroll
    for (int p = 0; p < 8; ++p) {
      int flat = p * 256 + tid;
      int r = flat >> 4, cc = flat & 15;
      uint2 w2 = *(const uint2*)(WxT + (size_t)(n0 + r) * 256 + k0 + cc * 4);
      *(uint2*)&Bl[r * 72 + cc * 4] = w2;
    }
    __syncthreads();
#pragma unroll
    for (int kk = 0; kk < 64; kk += 32) {
      f16x8 af[4], bfr[4];
#pragma unroll
      for (int i = 0; i < 4; ++i) {
        af[i]  = lds16(&Al[(wr * 64 + i * 16 + (lane & 15)) * 72 + kk + (lane >> 4) * 8]);
        bfr[i] = lds16(&Bl[(wc * 64 + i * 16 + (lane & 15)) * 72 + kk + (lane >> 4) * 8]);
      }
#pragma unroll
      for (int mi = 0; mi < 4; ++mi)
#pragma unroll
        for (int ni = 0; ni < 4; ++ni)
          acc[mi][ni] = __builtin_amdgcn_mfma_f32_16x16x32_f16(af[mi], bfr[ni], acc[mi][ni], 0, 0, 0);
    }
    __syncthreads();
  }
#pragma unroll
  for (int ni = 0; ni < 4; ++ni) {
    int n = n0 + wc * 64 + ni * 16 + (lane & 15);
    int g = n >> 8;
    const float* bp = (g == 0) ? bi : (g == 1) ? bf : (g == 2) ? bg : bo;
    float bias = bp[n & 255];
    const int nperm = (n & 255) * 4 + g;
#pragma unroll
    for (int mi = 0; mi < 4; ++mi) {
#pragma unroll
      for (int ri = 0; ri < 4; ++ri) {
        int m = m0 + wr * 64 + mi * 16 + (lane >> 4) * 4 + ri;
        gates[(size_t)m * 1024 + nperm] = f16bits(acc[mi][ni][ri] + bias);
      }
    }
  }
}

// ---------------- persistent per-batch recurrence ----------------------------
// 1024 threads. thread t (w=t>>6, l=t&63, q=l>>4): owns hidden unit
// hcol=w*16+(l&15), computes K-quarter-q partial dots for its 4 gate columns.
// qreduce (permlane, VALU pipe) gives full z in all lanes -> inline c/h update.
// Weight pairs: pp 0..5 in regs (96 u32 — R2-proven reg-share ceiling),
// pp 6..7 in LDS ([8][1024] uint4). ONE barrier per step.
__global__ __launch_bounds__(1024) void lstm_rec(
    const u32* __restrict__ Whpp, const u16* __restrict__ gates,
    u32* __restrict__ h16s, float* __restrict__ c_s,
    const float* __restrict__ Why, const float* __restrict__ by,
    float* __restrict__ out, int Tc, int last) {
  extern __shared__ unsigned char smem[];
  uint4* ldsW = (uint4*)smem;                       // [8][1024] uint4 = 131072 B
  u32*   hq   = (u32*)(smem + 131072);              // [2][4*40] u32   = 1280 B
  const int b = blockIdx.x, t = threadIdx.x;
  const int l = t & 63, w = t >> 6, q = l >> 4;
  const int hcol = w * 16 + (l & 15);

  // gather weights: 32 coalesced uint4 loads; pp<6 -> regs, pp>=6 -> LDS
  u32 wreg[96];
  const uint4* Wp4 = (const uint4*)Whpp;
#pragma unroll
  for (int i4 = 0; i4 < 32; ++i4) {
    uint4 v = Wp4[i4 * 1024 + t];
    const int g = i4 >> 3, pp = i4 & 7;
    if (pp < 6) {
      wreg[g * 24 + pp * 4 + 0] = v.x;
      wreg[g * 24 + pp * 4 + 1] = v.y;
      wreg[g * 24 + pp * 4 + 2] = v.z;
      wreg[g * 24 + pp * 4 + 3] = v.w;
    } else {
      ldsW[(g * 2 + (pp - 6)) * 1024 + t] = v;
    }
  }
  if (t < 128) hq[(t >> 5) * 40 + (t & 31)] = h16s[b * 128 + t];
  float c = c_s[b * 256 + hcol];                    // replicated across quarters
  const u16* gxp = gates + (size_t)b * Tc * 1024 + hcol * 4;
  uint2 pre = *(const uint2*)gxp;
  int buf = 0;
  __syncthreads();

  for (int tc = 0; tc < Tc; ++tc) {
    const uint2 gx = pre;
    if (tc + 1 < Tc) pre = *(const uint2*)(gxp + (size_t)(tc + 1) * 1024);
    float acc0 = 0.f, acc1 = 0.f, acc2 = 0.f, acc3 = 0.f;
    const uint4* hb = (const uint4*)(hq + buf * 160 + q * 40);
#pragma unroll
    for (int u = 0; u < 8; ++u) {
      uint4 hv = hb[u];
      uint4 w0, w1, w2, w3;
      if (u < 6) {
        w0 = make_uint4(wreg[0 * 24 + u * 4], wreg[0 * 24 + u * 4 + 1], wreg[0 * 24 + u * 4 + 2], wreg[0 * 24 + u * 4 + 3]);
        w1 = make_uint4(wreg[1 * 24 + u * 4], wreg[1 * 24 + u * 4 + 1], wreg[1 * 24 + u * 4 + 2], wreg[1 * 24 + u * 4 + 3]);
        w2 = make_uint4(wreg[2 * 24 + u * 4], wreg[2 * 24 + u * 4 + 1], wreg[2 * 24 + u * 4 + 2], wreg[2 * 24 + u * 4 + 3]);
        w3 = make_uint4(wreg[3 * 24 + u * 4], wreg[3 * 24 + u * 4 + 1], wreg[3 * 24 + u * 4 + 2], wreg[3 * 24 + u * 4 + 3]);
      } else {
        w0 = ldsW[(0 * 2 + u - 6) * 1024 + t];
        w1 = ldsW[(1 * 2 + u - 6) * 1024 + t];
        w2 = ldsW[(2 * 2 + u - 6) * 1024 + t];
        w3 = ldsW[(3 * 2 + u - 6) * 1024 + t];
      }
      acc0 = fdot2a(hv.x, w0.x, acc0); acc0 = fdot2a(hv.y, w0.y, acc0);
      acc0 = fdot2a(hv.z, w0.z, acc0); acc0 = fdot2a(hv.w, w0.w, acc0);
      acc1 = fdot2a(hv.x, w1.x, acc1); acc1 = fdot2a(hv.y, w1.y, acc1);
      acc1 = fdot2a(hv.z, w1.z, acc1); acc1 = fdot2a(hv.w, w1.w, acc1);
      acc2 = fdot2a(hv.x, w2.x, acc2); acc2 = fdot2a(hv.y, w2.y, acc2);
      acc2 = fdot2a(hv.z, w2.z, acc2); acc2 = fdot2a(hv.w, w2.w, acc2);
      acc3 = fdot2a(hv.x, w3.x, acc3); acc3 = fdot2a(hv.y, w3.y, acc3);
      acc3 = fdot2a(hv.w, w3.w, acc3); acc3 = fdot2a(hv.z, w3.z, acc3);
    }
    // VALU-pipe cross-quarter reduction: all lanes get the complete sums
    acc0 = qreduce(acc0);
    acc1 = qreduce(acc1);
    acc2 = qreduce(acc2);
    acc3 = qreduce(acc3);
    // inline gate math (identical in all 4 quarter lanes of this unit)
    float zi = acc0 + h2f((u16)(gx.x & 0xffff));
    float zf = acc1 + h2f((u16)(gx.x >> 16));
    float zg = acc2 + h2f((u16)(gx.y & 0xffff));
    float zo = acc3 + h2f((u16)(gx.y >> 16));
    float i_ = sigmoidf_(zi), f_ = sigmoidf_(zf), g_ = tanhf_(zg), o_ = sigmoidf_(zo);
    c = f_ * c + i_ * g_;
    float h_ = o_ * tanhf_(c);
    if (l < 16) {                                   // q==0 publishes h
      const int kk = hcol >> 1;
      ((u16*)hq)[((buf ^ 1) * 160 + (kk >> 5) * 40 + (kk & 31)) * 2 + (hcol & 1)] = f16bits(h_);
    }
    buf ^= 1;
    __syncthreads();
  }

  if (t < 128) h16s[b * 128 + t] = hq[buf * 160 + (t >> 5) * 40 + (t & 31)];
  if (l < 16) c_s[b * 256 + hcol] = c;

  if (last && t < 128) {                    // y = h_T @ W_hy + b_y
    float acc = by[t];
    const u16* hh = (const u16*)(hq + buf * 160);
#pragma unroll 8
    for (int k = 0; k < 256; ++k) {
      float hv = h2f(hh[((k >> 6) * 40 + ((k >> 1) & 31)) * 2 + (k & 1)]);
      acc += hv * Why[k * 128 + t];
    }
    out[b * 128 + t] = acc;
  }
}

extern "C" void kernel_launch(void* const* d_in, const int* in_sizes, int n_in,
                              void* d_out, int out_size, void* d_ws, size_t ws_size,
                              hipStream_t stream) {
  const float* x   = (const float*)d_in[0];
  const float* Wxi = (const float*)d_in[1];
  const float* Whi = (const float*)d_in[2];
  const float* b_i = (const float*)d_in[3];
  const float* Wxf = (const float*)d_in[4];
  const float* Whf = (const float*)d_in[5];
  const float* b_f = (const float*)d_in[6];
  const float* Wxg = (const float*)d_in[7];
  const float* Whg = (const float*)d_in[8];
  const float* b_g = (const float*)d_in[9];
  const float* Wxo = (const float*)d_in[10];
  const float* Who = (const float*)d_in[11];
  const float* b_o = (const float*)d_in[12];
  const float* Why = (const float*)d_in[13];
  const float* b_y = (const float*)d_in[14];
  float* out = (float*)d_out;

  int Tc = 256;
  while (Tc > 32 && (size_t)128 * Tc * 1024 * 2 + 1245184ull > ws_size) Tc >>= 1;
  const int tcShift = __builtin_ctz((unsigned)Tc);
  const int nch = 1024 / Tc;

  char* wsb = (char*)d_ws;
  const size_t gbytes = (size_t)128 * Tc * 1024 * 2;
  u16*   gates16 = (u16*)wsb;
  u16*   WxT     = (u16*)(wsb + gbytes);
  u32*   Whpp    = (u32*)(wsb + gbytes + 524288);
  u32*   h16s    = (u32*)(wsb + gbytes + 1048576);
  float* c_s     = (float*)(wsb + gbytes + 1048576 + 65536);

  const int recLds = 131072 + 1280;
  (void)hipFuncSetAttribute((const void*)lstm_rec,
                            hipFuncAttributeMaxDynamicSharedMemorySize, recLds);

  lstm_prep<<<1728, 256, 0, stream>>>(Wxi, Wxf, Wxg, Wxo, Whi, Whf, Whg, Who,
                                      WxT, Whpp, h16s, c_s);
  for (int ci = 0; ci < nch; ++ci) {
    int t0 = ci * Tc;
    proj_gemm<<<dim3(Tc, 8), 256, 0, stream>>>(x, WxT, gates16, b_i, b_f, b_g, b_o,
                                               t0, tcShift);
    lstm_rec<<<128, 1024, recLds, stream>>>(Whpp, gates16, h16s, c_s, Why, b_y, out,
                                            Tc, (ci == nch - 1) ? 1 : 0);
  }
}

// Round 5
// 2511.280 us; speedup vs baseline: 1.7381x; 1.0422x over previous
//
#include <hip/hip_runtime.h>

using u16 = unsigned short;
using u32 = unsigned int;

typedef _Float16 f16x2 __attribute__((ext_vector_type(2)));
typedef _Float16 f16x8 __attribute__((ext_vector_type(8)));
typedef float    f32x4 __attribute__((ext_vector_type(4)));

__device__ __forceinline__ u16 f16bits(float x) {
  union { _Float16 h; u16 u; } r; r.h = (_Float16)x; return r.u;
}
__device__ __forceinline__ float h2f(u16 v) {
  union { u16 u; _Float16 h; } r; r.u = v; return (float)r.h;
}
__device__ __forceinline__ u32 pack2(float a, float b) {
  union { f16x2 h; u32 u; } r; r.h.x = (_Float16)a; r.h.y = (_Float16)b; return r.u;
}
__device__ __forceinline__ float fdot2a(u32 a, u32 b, float c) {
  union { u32 u; f16x2 h; } ua, ub; ua.u = a; ub.u = b;
#if __has_builtin(__builtin_amdgcn_fdot2)
  return __builtin_amdgcn_fdot2(ua.h, ub.h, c, false);
#else
  return c + (float)ua.h.x * (float)ub.h.x + (float)ua.h.y * (float)ub.h.y;
#endif
}
__device__ __forceinline__ float sigmoidf_(float x) { return 1.0f / (1.0f + __expf(-x)); }
__device__ __forceinline__ float tanhf_(float x)    { return 1.0f - 2.0f / (__expf(2.0f * x) + 1.0f); }

__device__ __forceinline__ f16x8 lds16(const u16* p) {
  union { uint4 u; f16x8 h; } r; r.u = *(const uint4*)p; return r.h;
}

// Cross-quarter reduce on the VALU pipe (permlane swaps), not LDS (bpermute).
__device__ __forceinline__ float qreduce(float a) {
#if __has_builtin(__builtin_amdgcn_permlane16_swap) && __has_builtin(__builtin_amdgcn_permlane32_swap)
  typedef unsigned uv2 __attribute__((ext_vector_type(2)));
  union { float f; unsigned u; } x, p, q;
  x.f = a;
  uv2 r1 = __builtin_amdgcn_permlane16_swap(x.u, x.u, false, false);
  p.u = r1[0]; q.u = r1[1];
  float s = p.f + q.f;
  x.f = s;
  uv2 r2 = __builtin_amdgcn_permlane32_swap(x.u, x.u, false, false);
  p.u = r2[0]; q.u = r2[1];
  return p.f + q.f;
#else
  a += __shfl_xor(a, 16);
  a += __shfl_xor(a, 32);
  return a;
#endif
}

// ---------------- prep: build f16 weight layouts + zero state ----------------
// WxT[n][k]   : [1024][256] f16, transposed input-proj weights
// Whpp[i4][t] : [64][512] uint4 — per-(rec-)thread gathered W_h pair groups.
//   rec thread t (of 512): w=t>>6, l=t&63, q=l>>4, us=w*16+(l&15);
//   i4 = (uu*4+g)*8+pp; unit=(us*2+uu); element e = f16x2 pair kk=q*32+pp*4+e
//   of column `unit` of gate-g W_h.
// h16s        : [128][128] u32 pairs of h state, zeroed
// c_s         : [128][256] f32, zeroed
__global__ void lstm_prep(const float* __restrict__ Wxi, const float* __restrict__ Wxf,
                          const float* __restrict__ Wxg, const float* __restrict__ Wxo,
                          const float* __restrict__ Whi, const float* __restrict__ Whf,
                          const float* __restrict__ Whg, const float* __restrict__ Who,
                          u16* __restrict__ WxT, u32* __restrict__ Whpp,
                          u32* __restrict__ h16s, float* __restrict__ c_s) {
  int idx = blockIdx.x * 256 + threadIdx.x;
  if (idx < 262144) {                       // WxT
    int n = idx >> 8, k = idx & 255;
    int g = n >> 8;
    const float* W = (g == 0) ? Wxi : (g == 1) ? Wxf : (g == 2) ? Wxg : Wxo;
    WxT[idx] = f16bits(W[k * 256 + (n & 255)]);
  } else if (idx < 262144 + 131072) {       // Whpp (u32-granular writes)
    int i2 = idx - 262144;
    int e = i2 & 3, tmp = i2 >> 2;
    int t = tmp & 511, i4 = tmp >> 9;       // t in [0,512), i4 in [0,64)
    int pp = i4 & 7, ug = i4 >> 3;          // ug = uu*4+g
    int g = ug & 3, uu = ug >> 2;
    int w = t >> 6, l = t & 63, q = l >> 4;
    int unit = (w * 16 + (l & 15)) * 2 + uu;
    int kk = q * 32 + pp * 4 + e;
    const float* W = (g == 0) ? Whi : (g == 1) ? Whf : (g == 2) ? Whg : Who;
    u32 lo = f16bits(W[(2 * kk) * 256 + unit]);
    u32 hi = f16bits(W[(2 * kk + 1) * 256 + unit]);
    Whpp[i2] = lo | (hi << 16);
  } else if (idx < 262144 + 131072 + 16384) {
    h16s[idx - 393216] = 0u;
  } else if (idx < 262144 + 131072 + 16384 + 32768) {
    c_s[idx - 409600] = 0.0f;
  }
}

// ---------------- input-projection GEMM --------------------------------------
// Epilogue writes PERMUTED gate layout: gates[m][ (n&255)*4 + (n>>8) ], so the
// recurrence loads all 8 gate pre-acts of its 2 units as one uint4.
__global__ __launch_bounds__(256) void proj_gemm(
    const float* __restrict__ x, const u16* __restrict__ WxT,
    u16* __restrict__ gates, const float* __restrict__ bi,
    const float* __restrict__ bf, const float* __restrict__ bg,
    const float* __restrict__ bo, int t0, int tcShift) {
  __shared__ u16 Al[128 * 72];
  __shared__ u16 Bl[128 * 72];
  const int tid = threadIdx.x;
  const int lane = tid & 63, wv = tid >> 6;
  const int wr = wv >> 1, wc = wv & 1;
  const int m0 = blockIdx.x * 128, n0 = blockIdx.y * 128;
  const int tcMask = (1 << tcShift) - 1;
  f32x4 acc[4][4] = {};
  for (int k0 = 0; k0 < 256; k0 += 64) {
#pragma unroll
    for (int p = 0; p < 8; ++p) {
      int flat = p * 256 + tid;
      int r = flat >> 4, cc = flat & 15;
      int m = m0 + r;
      int b = m >> tcShift, tc = m & tcMask;
      const float4 xv = *(const float4*)(x + (size_t)(b * 1024 + t0 + tc) * 256 + k0 + cc * 4);
      uint2 w2 = make_uint2(pack2(xv.x, xv.y), pack2(xv.z, xv.w));
      *(uint2*)&Al[r * 72 + cc * 4] = w2;
    }
#pragma unroll
    for (int p = 0; p < 8; ++p) {
      int flat = p * 256 + tid;
      int r = flat >> 4, cc = flat & 15;
      uint2 w2 = *(const uint2*)(WxT + (size_t)(n0 + r) * 256 + k0 + cc * 4);
      *(uint2*)&Bl[r * 72 + cc * 4] = w2;
    }
    __syncthreads();
#pragma unroll
    for (int kk = 0; kk < 64; kk += 32) {
      f16x8 af[4], bfr[4];
#pragma unroll
      for (int i = 0; i < 4; ++i) {
        af[i]  = lds16(&Al[(wr * 64 + i * 16 + (lane & 15)) * 72 + kk + (lane >> 4) * 8]);
        bfr[i] = lds16(&Bl[(wc * 64 + i * 16 + (lane & 15)) * 72 + kk + (lane >> 4) * 8]);
      }
#pragma unroll
      for (int mi = 0; mi < 4; ++mi)
#pragma unroll
        for (int ni = 0; ni < 4; ++ni)
          acc[mi][ni] = __builtin_amdgcn_mfma_f32_16x16x32_f16(af[mi], bfr[ni], acc[mi][ni], 0, 0, 0);
    }
    __syncthreads();
  }
#pragma unroll
  for (int ni = 0; ni < 4; ++ni) {
    int n = n0 + wc * 64 + ni * 16 + (lane & 15);
    int g = n >> 8;
    const float* bp = (g == 0) ? bi : (g == 1) ? bf : (g == 2) ? bg : bo;
    float bias = bp[n & 255];
    const int nperm = (n & 255) * 4 + g;
#pragma unroll
    for (int mi = 0; mi < 4; ++mi) {
#pragma unroll
      for (int ri = 0; ri < 4; ++ri) {
        int m = m0 + wr * 64 + mi * 16 + (lane >> 4) * 4 + ri;
        gates[(size_t)m * 1024 + nperm] = f16bits(acc[mi][ni][ri] + bias);
      }
    }
  }
}

// ---------------- persistent per-batch recurrence ----------------------------
// 512 threads, 8 waves, 2 waves/SIMD -> 256-reg budget per thread.
// Thread t (w=t>>6, l=t&63, q=l>>4, us=w*16+(l&15)): owns units u0=2us, u1=2us+1
// for all 4 gates, K-quarter q. Weights: pp 0..5 in regs (192 u32),
// pp 6..7 in LDS ([16][512] uint4 = 128 KB). qreduce gives full z in all lanes
// -> inline c/h update; q==0 lanes publish BOTH units' h as one packed u32.
// ONE barrier per step.
__global__ __launch_bounds__(512, 2) void lstm_rec(
    const u32* __restrict__ Whpp, const u16* __restrict__ gates,
    u32* __restrict__ h16s, float* __restrict__ c_s,
    const float* __restrict__ Why, const float* __restrict__ by,
    float* __restrict__ out, int Tc, int last) {
  extern __shared__ unsigned char smem[];
  uint4* ldsW = (uint4*)smem;                       // [16][512] uint4 = 131072 B
  u32*   hq   = (u32*)(smem + 131072);              // [2][4*40] u32   = 1280 B
  const int b = blockIdx.x, t = threadIdx.x;
  const int l = t & 63, w = t >> 6, q = l >> 4;
  const int us = w * 16 + (l & 15);                 // unit-slot: units 2us, 2us+1

  // gather weights: 64 coalesced uint4 loads; pp<6 -> regs, pp>=6 -> LDS
  u32 wreg[192];
  const uint4* Wp4 = (const uint4*)Whpp;
#pragma unroll
  for (int i4 = 0; i4 < 64; ++i4) {
    uint4 v = Wp4[i4 * 512 + t];
    const int ug = i4 >> 3, pp = i4 & 7;
    if (pp < 6) {
      wreg[ug * 24 + pp * 4 + 0] = v.x;
      wreg[ug * 24 + pp * 4 + 1] = v.y;
      wreg[ug * 24 + pp * 4 + 2] = v.z;
      wreg[ug * 24 + pp * 4 + 3] = v.w;
    } else {
      ldsW[(ug * 2 + (pp - 6)) * 512 + t] = v;
    }
  }
  if (t < 128) hq[(t >> 5) * 40 + (t & 31)] = h16s[b * 128 + t];
  float c0 = c_s[b * 256 + us * 2];
  float c1 = c_s[b * 256 + us * 2 + 1];
  const u16* gxp = gates + (size_t)b * Tc * 1024 + us * 8;
  uint4 pre = *(const uint4*)gxp;
  int buf = 0;
  __syncthreads();

  for (int tc = 0; tc < Tc; ++tc) {
    const uint4 gx = pre;
    if (tc + 1 < Tc) pre = *(const uint4*)(gxp + (size_t)(tc + 1) * 1024);
    float acc[8];
#pragma unroll
    for (int i = 0; i < 8; ++i) acc[i] = 0.0f;
    const uint4* hb = (const uint4*)(hq + buf * 160 + q * 40);
#pragma unroll
    for (int pp = 0; pp < 8; ++pp) {
      uint4 hv = hb[pp];
      if (pp < 6) {
#pragma unroll
        for (int ug = 0; ug < 8; ++ug) {
          acc[ug] = fdot2a(hv.x, wreg[ug * 24 + pp * 4 + 0], acc[ug]);
          acc[ug] = fdot2a(hv.y, wreg[ug * 24 + pp * 4 + 1], acc[ug]);
          acc[ug] = fdot2a(hv.z, wreg[ug * 24 + pp * 4 + 2], acc[ug]);
          acc[ug] = fdot2a(hv.w, wreg[ug * 24 + pp * 4 + 3], acc[ug]);
        }
      } else {
#pragma unroll
        for (int ug = 0; ug < 8; ++ug) {
          uint4 wv = ldsW[(ug * 2 + (pp - 6)) * 512 + t];
          acc[ug] = fdot2a(hv.x, wv.x, acc[ug]);
          acc[ug] = fdot2a(hv.y, wv.y, acc[ug]);
          acc[ug] = fdot2a(hv.z, wv.z, acc[ug]);
          acc[ug] = fdot2a(hv.w, wv.w, acc[ug]);
        }
      }
    }
    // VALU-pipe cross-quarter reduction: all lanes get complete sums
#pragma unroll
    for (int i = 0; i < 8; ++i) acc[i] = qreduce(acc[i]);
    // unit 0 (ug 0..3): gate pre-acts in gx.x(lo,hi), gx.y(lo,hi)
    float zi0 = acc[0] + h2f((u16)(gx.x & 0xffff));
    float zf0 = acc[1] + h2f((u16)(gx.x >> 16));
    float zg0 = acc[2] + h2f((u16)(gx.y & 0xffff));
    float zo0 = acc[3] + h2f((u16)(gx.y >> 16));
    // unit 1 (ug 4..7): gx.z(lo,hi), gx.w(lo,hi)
    float zi1 = acc[4] + h2f((u16)(gx.z & 0xffff));
    float zf1 = acc[5] + h2f((u16)(gx.z >> 16));
    float zg1 = acc[6] + h2f((u16)(gx.w & 0xffff));
    float zo1 = acc[7] + h2f((u16)(gx.w >> 16));
    float i0 = sigmoidf_(zi0), f0 = sigmoidf_(zf0), g0 = tanhf_(zg0), o0 = sigmoidf_(zo0);
    float i1 = sigmoidf_(zi1), f1 = sigmoidf_(zf1), g1 = tanhf_(zg1), o1 = sigmoidf_(zo1);
    c0 = f0 * c0 + i0 * g0;
    c1 = f1 * c1 + i1 * g1;
    float h0 = o0 * tanhf_(c0);
    float h1 = o1 * tanhf_(c1);
    if (l < 16) {                                   // q==0 publishes the h pair
      hq[(buf ^ 1) * 160 + (us >> 5) * 40 + (us & 31)] = pack2(h0, h1);
    }
    buf ^= 1;
    __syncthreads();
  }

  if (t < 128) h16s[b * 128 + t] = hq[buf * 160 + (t >> 5) * 40 + (t & 31)];
  if (l < 16) {
    c_s[b * 256 + us * 2]     = c0;
    c_s[b * 256 + us * 2 + 1] = c1;
  }

  if (last && t < 128) {                    // y = h_T @ W_hy + b_y
    float acc = by[t];
    const u16* hh = (const u16*)(hq + buf * 160);
#pragma unroll 8
    for (int k = 0; k < 256; ++k) {
      float hv = h2f(hh[((k >> 6) * 40 + ((k >> 1) & 31)) * 2 + (k & 1)]);
      acc += hv * Why[k * 128 + t];
    }
    out[b * 128 + t] = acc;
  }
}

extern "C" void kernel_launch(void* const* d_in, const int* in_sizes, int n_in,
                              void* d_out, int out_size, void* d_ws, size_t ws_size,
                              hipStream_t stream) {
  const float* x   = (const float*)d_in[0];
  const float* Wxi = (const float*)d_in[1];
  const float* Whi = (const float*)d_in[2];
  const float* b_i = (const float*)d_in[3];
  const float* Wxf = (const float*)d_in[4];
  const float* Whf = (const float*)d_in[5];
  const float* b_f = (const float*)d_in[6];
  const float* Wxg = (const float*)d_in[7];
  const float* Whg = (const float*)d_in[8];
  const float* b_g = (const float*)d_in[9];
  const float* Wxo = (const float*)d_in[10];
  const float* Who = (const float*)d_in[11];
  const float* b_o = (const float*)d_in[12];
  const float* Why = (const float*)d_in[13];
  const float* b_y = (const float*)d_in[14];
  float* out = (float*)d_out;

  int Tc = 256;
  while (Tc > 32 && (size_t)128 * Tc * 1024 * 2 + 1245184ull > ws_size) Tc >>= 1;
  const int tcShift = __builtin_ctz((unsigned)Tc);
  const int nch = 1024 / Tc;

  char* wsb = (char*)d_ws;
  const size_t gbytes = (size_t)128 * Tc * 1024 * 2;
  u16*   gates16 = (u16*)wsb;
  u16*   WxT     = (u16*)(wsb + gbytes);
  u32*   Whpp    = (u32*)(wsb + gbytes + 524288);
  u32*   h16s    = (u32*)(wsb + gbytes + 1048576);
  float* c_s     = (float*)(wsb + gbytes + 1048576 + 65536);

  const int recLds = 131072 + 1280;
  (void)hipFuncSetAttribute((const void*)lstm_rec,
                            hipFuncAttributeMaxDynamicSharedMemorySize, recLds);

  lstm_prep<<<1728, 256, 0, stream>>>(Wxi, Wxf, Wxg, Wxo, Whi, Whf, Whg, Who,
                                      WxT, Whpp, h16s, c_s);
  for (int ci = 0; ci < nch; ++ci) {
    int t0 = ci * Tc;
    proj_gemm<<<dim3(Tc, 8), 256, 0, stream>>>(x, WxT, gates16, b_i, b_f, b_g, b_o,
                                               t0, tcShift);
    lstm_rec<<<128, 512, recLds, stream>>>(Whpp, gates16, h16s, c_s, Why, b_y, out,
                                           Tc, (ci == nch - 1) ? 1 : 0);
  }
}